// Round 6
// baseline (223.028 us; speedup 1.0000x reference)
//
#include <hip/hip_runtime.h>
#include <hip/hip_bf16.h>
#include <math.h>

#define DD 128
#define CAP 64      // bucket capacity per node; deg ~ Poisson(16)
#define LDSP 136    // padded LDS row: 128+8 bf16 -> 272 B stride
#define NSHARD 8    // = #XCDs; shard = blockIdx&7 keeps cnt/slot region XCD-local
#define FILL_BLOCKS 4096   // 512 chunks x 8 shards (round-1 measured config)
#define PACK_BLOCKS 256

typedef __attribute__((ext_vector_type(8))) short short8;
typedef __attribute__((ext_vector_type(4))) float floatx4;
typedef __attribute__((ext_vector_type(8))) unsigned short ushortx8;

static __device__ __forceinline__ unsigned pack2bf(float a, float b) {
    __hip_bfloat16 ba = __float2bfloat16(a), bb = __float2bfloat16(b);
    return (unsigned)*(ushort*)&ba | ((unsigned)*(ushort*)&bb << 16);
}
#define BF2F(u) __uint_as_float((unsigned)(u) << 16)

// ---------------- fused prep: XCD-sharded CSR fill + x->bf16 cast + W pack ----------
// Fill: shard = b&7 (dst range stays in one XCD's L2 so the scatter stores coalesce
// there — round 2 measured un-sharded at +16MB WRITE / +14us). slot is ushort
// (src < 50000 < 2^16): halves scatter bytes and agg index-load bytes.
__global__ __launch_bounds__(256) void prep_kernel(
        const float* __restrict__ x,
        const int* __restrict__ src, const int* __restrict__ dst,
        int* __restrict__ cnt, ushort* __restrict__ slot,
        const float* __restrict__ W1a, const float* __restrict__ W1b,
        const float* __restrict__ W2a, const float* __restrict__ W2b,
        ushort* __restrict__ Wp1, ushort* __restrict__ Wp2,
        ushort* __restrict__ Xb,
        int E, int n8, int shard_size, int cast_blocks) {
    int b = blockIdx.x;
    if (b < FILL_BLOCKS) {
        int shard = b & (NSHARD - 1);
        int chunk = b >> 3;
        int lo = shard * shard_size;
        int hi = lo + shard_size;
        const int stride = (FILL_BLOCKS >> 3) * 256;
        int e = chunk * 256 + threadIdx.x;
        for (; e + 3 * stride < E; e += 4 * stride) {
            int d0 = dst[e];
            int d1 = dst[e + stride];
            int d2 = dst[e + 2 * stride];
            int d3 = dst[e + 3 * stride];
            if (d0 >= lo && d0 < hi) {
                int p = atomicAdd(&cnt[d0], 1);
                if (p < CAP) slot[(size_t)d0 * CAP + p] = (ushort)src[e];
            }
            if (d1 >= lo && d1 < hi) {
                int p = atomicAdd(&cnt[d1], 1);
                if (p < CAP) slot[(size_t)d1 * CAP + p] = (ushort)src[e + stride];
            }
            if (d2 >= lo && d2 < hi) {
                int p = atomicAdd(&cnt[d2], 1);
                if (p < CAP) slot[(size_t)d2 * CAP + p] = (ushort)src[e + 2 * stride];
            }
            if (d3 >= lo && d3 < hi) {
                int p = atomicAdd(&cnt[d3], 1);
                if (p < CAP) slot[(size_t)d3 * CAP + p] = (ushort)src[e + 3 * stride];
            }
        }
        for (; e < E; e += stride) {
            int d = dst[e];
            if (d >= lo && d < hi) {
                int p = atomicAdd(&cnt[d], 1);
                if (p < CAP) slot[(size_t)d * CAP + p] = (ushort)src[e];
            }
        }
    } else if (b < FILL_BLOCKS + cast_blocks) {
        // ---- x (f32) -> Xb (bf16), 8 floats / thread ----
        int i = (b - FILL_BLOCKS) * 256 + threadIdx.x;
        if (i < n8) {
            const float4* xp = (const float4*)x;
            float4 v0 = xp[(size_t)i * 2];
            float4 v1 = xp[(size_t)i * 2 + 1];
            uint4 o;
            o.x = pack2bf(v0.x, v0.y);
            o.y = pack2bf(v0.z, v0.w);
            o.z = pack2bf(v1.x, v1.y);
            o.w = pack2bf(v1.z, v1.w);
            *(uint4*)&Xb[(size_t)i * 8] = o;
        }
    } else {
        // ---- pack stacked W = [Wself; Wneigh] (256x128) into MFMA B-frag layout ----
        // Wp[((ks*8+nt)*64+lane)*8+j] = W[ks*32+(lane>>4)*8+j][nt*16+(lane&15)]
        int gid = (b - FILL_BLOCKS - cast_blocks) * 256 + threadIdx.x;  // 0..65535
        int layer = gid >> 15;
        int r = gid & 32767;
        int j = r & 7;
        int lane = (r >> 3) & 63;
        int nt = (r >> 9) & 7;
        int ks = r >> 12;
        int k = ks * 32 + (lane >> 4) * 8 + j;
        int col = nt * 16 + (lane & 15);
        const float* W = layer ? (k < 128 ? W2a : W2b) : (k < 128 ? W1a : W1b);
        __hip_bfloat16 bf = __float2bfloat16(W[(k & 127) * DD + col]);
        (layer ? Wp2 : Wp1)[r] = *(ushort*)&bf;
    }
}

// ---------------- fused SAGE layer: agg(mean neigh)->LDS -> MFMA GEMM --------------
// One block = one 16-row strip. Each 16-lane GROUP owns one node end-to-end
// (16 lanes x 16 B = full 256 B row; accumulator lives across the degree walk).
// Degree walk: 8 STATIC batches of 8 rows. Static unroll -> each batch issues all
// 8 row-loads before the accumulate (round 5's dynamic `for(s<nin;s+=4)` loop
// couldn't pipeline: 4 serial rounds of 4 loads for deg=16; now 2 rounds of 8).
// Clamped source lanes + 0/1 weights keep shfl sources active; idx-register
// index (b8>>1) is compile-time -> no scratch (rule #20).
__global__ __launch_bounds__(256) void sage_layer_kernel(
        const ushort* __restrict__ Xin, const int* __restrict__ cnt,
        const ushort* __restrict__ slot, const ushort* __restrict__ Wp,
        const float* __restrict__ bias,
        ushort* __restrict__ out_bf16, float* __restrict__ out_f32,
        int n, int do_elu) {
    __shared__ ushort hn[16 * LDSP];   // 4.25 KB

    const int row0 = blockIdx.x * 16;
    const int w    = threadIdx.x >> 6;   // wave 0..3
    const int lane = threadIdx.x & 63;
    const int g  = lane >> 4;            // group 0..3: owns node row0 + w*4 + g
    const int sl = lane & 15;
    const int c  = sl * 8;

    const int vg = row0 + w * 4 + g;
    int d = (vg < n) ? cnt[vg] : 0;
    if (d > CAP) d = CAP;

    // neighbor indices for this group's node: reg r holds slots r*16 + sl
    const ushort* sp = slot + (size_t)(vg < n ? vg : 0) * CAP;
    int idxv[4];
#pragma unroll
    for (int r = 0; r < 4; ++r) idxv[r] = sp[r * 16 + sl];

    float acc[8];
#pragma unroll
    for (int j = 0; j < 8; ++j) acc[j] = 0.f;

#pragma unroll
    for (int b8 = 0; b8 < 8; ++b8) {        // static batches of 8 neighbor rows
        const int base = b8 * 8;
        if (base < d) {                      // group-uniform (exec-masked per group)
            const int rr = b8 >> 1;          // compile-time under unroll
            int u[8];
            float wt[8];
#pragma unroll
            for (int k = 0; k < 8; ++k) {
                int i = base + k;
                int si = i < d ? i : d - 1;  // stays within chunk rr (si >= base)
                u[k] = __shfl(idxv[rr], g * 16 + (si & 15));
                wt[k] = i < d ? 1.f : 0.f;
            }
            ushortx8 y[8];
#pragma unroll
            for (int k = 0; k < 8; ++k)      // 8 independent 16B loads in flight
                y[k] = *(const ushortx8*)&Xin[(size_t)u[k] * DD + c];
#pragma unroll
            for (int k = 0; k < 8; ++k)
#pragma unroll
                for (int j = 0; j < 8; ++j)
                    acc[j] += wt[k] * BF2F((ushort)y[k][j]);
        }
    }

    // write this group's aggregated row (no cross-group reduce needed)
    {
        float inv = 1.0f / (float)(d > 0 ? d : 1);
        ushort tmp[8];
#pragma unroll
        for (int j = 0; j < 8; ++j) {
            __hip_bfloat16 bq = __float2bfloat16(acc[j] * inv);
            tmp[j] = *(ushort*)&bq;
        }
        uint4 ov;
        ov.x = (unsigned)tmp[0] | ((unsigned)tmp[1] << 16);
        ov.y = (unsigned)tmp[2] | ((unsigned)tmp[3] << 16);
        ov.z = (unsigned)tmp[4] | ((unsigned)tmp[5] << 16);
        ov.w = (unsigned)tmp[6] | ((unsigned)tmp[7] << 16);
        *(uint4*)&hn[(w * 4 + g) * LDSP + c] = ov;   // 272 B row stride
    }

    __syncthreads();

    // ---- gemm: wave w owns N-tiles {2w, 2w+1}; K=256 = [Xin strip rows | hn] ----
    const int m = lane & 15;
    const int quad = lane >> 4;
    int mrow = row0 + m; if (mrow >= n) mrow = n - 1;
    const ushort* xrow = Xin + (size_t)mrow * DD + quad * 8;
    const ushort* hrow = &hn[m * LDSP + quad * 8];

    floatx4 acc0 = (floatx4){0.f, 0.f, 0.f, 0.f};
    floatx4 acc1 = (floatx4){0.f, 0.f, 0.f, 0.f};
#pragma unroll
    for (int ks = 0; ks < 8; ++ks) {
        short8 a = (ks < 4) ? *(const short8*)(xrow + ks * 32)
                            : *(const short8*)(hrow + (ks - 4) * 32);
        const ushort* wp = Wp + ((size_t)(ks * 8) * 64 + lane) * 8;
        short8 b0 = *(const short8*)(wp + (size_t)(w * 2 + 0) * 512);
        short8 b1 = *(const short8*)(wp + (size_t)(w * 2 + 1) * 512);
        acc0 = __builtin_amdgcn_mfma_f32_16x16x32_bf16(a, b0, acc0, 0, 0, 0);
        acc1 = __builtin_amdgcn_mfma_f32_16x16x32_bf16(a, b1, acc1, 0, 0, 0);
    }
    // C layout: col = nt*16 + (lane&15), row = quad*4 + reg
#pragma unroll
    for (int q = 0; q < 2; ++q) {
        int nt = w * 2 + q;
        int col = nt * 16 + m;
        float bv = bias[col];
        floatx4 av = q ? acc1 : acc0;
#pragma unroll
        for (int r = 0; r < 4; ++r) {
            int row = row0 + quad * 4 + r;
            if (row < n) {
                float vv = av[r] + bv;
                if (do_elu) vv = vv > 0.f ? vv : expm1f(vv);
                if (out_f32) {
                    out_f32[(size_t)row * DD + col] = vv;
                } else {
                    __hip_bfloat16 bq = __float2bfloat16(vv);
                    out_bf16[(size_t)row * DD + col] = *(ushort*)&bq;
                }
            }
        }
    }
}

// ---------------- launch ----------------

extern "C" void kernel_launch(void* const* d_in, const int* in_sizes, int n_in,
                              void* d_out, int out_size, void* d_ws, size_t ws_size,
                              hipStream_t stream) {
    const float* x   = (const float*)d_in[0];
    const int*   src = (const int*)d_in[1];
    const int*   dst = (const int*)d_in[2];
    const float* W1s = (const float*)d_in[3];
    const float* W1n = (const float*)d_in[4];
    const float* b1  = (const float*)d_in[5];
    const float* W2s = (const float*)d_in[6];
    const float* W2n = (const float*)d_in[7];
    const float* b2  = (const float*)d_in[8];
    float* out = (float*)d_out;

    const int N = in_sizes[0] / DD;
    const int E = in_sizes[1];

    char* ws = (char*)d_ws;
    int* cnt       = (int*)ws; ws += (size_t)N * 4;
    ushort* slot   = (ushort*)ws; ws += (size_t)N * CAP * 2;  // 6.4 MB (ushort src ids)
    ushort* Wp1    = (ushort*)ws; ws += 65536;                // 32768 bf16
    ushort* Wp2    = (ushort*)ws; ws += 65536;
    ushort* Xb     = (ushort*)ws; ws += (size_t)N * DD * 2;   // bf16 input
    ushort* H1     = (ushort*)ws; ws += (size_t)N * DD * 2;   // bf16 layer-1 output

    (void)hipMemsetAsync(cnt, 0, (size_t)N * 4, stream);

    // fused prep: sharded bucket fill + bf16 cast + W pack in ONE launch
    const int shard_size = (N + NSHARD - 1) / NSHARD;
    const int n8 = N * DD / 8;
    const int cast_blocks = (n8 + 255) / 256;
    prep_kernel<<<FILL_BLOCKS + cast_blocks + PACK_BLOCKS, 256, 0, stream>>>(
        x, src, dst, cnt, slot, W1s, W1n, W2s, W2n, Wp1, Wp2, Xb,
        E, n8, shard_size, cast_blocks);

    const int nstrips = (N + 15) / 16;              // 3125 (N=50000)

    // layer 1: H1 = ELU([Xb | mean_neigh(Xb)] @ W1 + b1)   (agg fused into gemm)
    sage_layer_kernel<<<nstrips, 256, 0, stream>>>(Xb, cnt, slot, Wp1, b1, H1, nullptr, N, 1);
    // layer 2: out = [H1 | mean_neigh(H1)] @ W2 + b2
    sage_layer_kernel<<<nstrips, 256, 0, stream>>>(H1, cnt, slot, Wp2, b2, nullptr, out, N, 0);
}

// Round 9
// 222.396 us; speedup vs baseline: 1.0028x; 1.0028x over previous
//
#include <hip/hip_runtime.h>
#include <hip/hip_bf16.h>
#include <math.h>

#define DD 128
#define CAP 64      // bucket capacity per node; deg ~ Poisson(16)
#define LDSP 136    // padded LDS row: 128+8 bf16 -> 272 B stride
#define NSHARD 8    // = #XCDs; shard = blockIdx&7 keeps cnt/slot region XCD-local
#define FILL_BLOCKS 4096   // 512 chunks x 8 shards (round-1 measured config)
#define PACK_BLOCKS 256

typedef __attribute__((ext_vector_type(8))) short short8;
typedef __attribute__((ext_vector_type(4))) float floatx4;
typedef __attribute__((ext_vector_type(8))) unsigned short ushortx8;

static __device__ __forceinline__ unsigned pack2bf(float a, float b) {
    __hip_bfloat16 ba = __float2bfloat16(a), bb = __float2bfloat16(b);
    return (unsigned)*(ushort*)&ba | ((unsigned)*(ushort*)&bb << 16);
}
#define BF2F(u) __uint_as_float((unsigned)(u) << 16)

// ---------------- fused prep: XCD-sharded CSR fill + x->bf16 cast + W pack ----------
// Fill: shard = b&7 (dst range stays in one XCD's L2 so scatter stores coalesce
// there — round 2 measured un-sharded at +16MB WRITE / +14us). slot is ushort.
// NEW (round 8): src loads HOISTED next to dst loads — 8 independent loads in
// flight before any branch/atomic. Previously src[e] sat inside the if AFTER the
// atomic (compiler can't speculate it), adding one serial memory latency to every
// in-shard edge's atomic->store chain. Costs ~22MB extra FETCH (src read per pass)
// but the fill runs at only ~20% HBM BW — bandwidth is free, latency is not.
// NOTE: __builtin_nontemporal_* killed the container in rounds 7 AND 8 — banned.
__global__ __launch_bounds__(256) void prep_kernel(
        const float* __restrict__ x,
        const int* __restrict__ src, const int* __restrict__ dst,
        int* __restrict__ cnt, ushort* __restrict__ slot,
        const float* __restrict__ W1a, const float* __restrict__ W1b,
        const float* __restrict__ W2a, const float* __restrict__ W2b,
        ushort* __restrict__ Wp1, ushort* __restrict__ Wp2,
        ushort* __restrict__ Xb,
        int E, int n8, int shard_size, int cast_blocks) {
    int b = blockIdx.x;
    if (b < FILL_BLOCKS) {
        int shard = b & (NSHARD - 1);
        int chunk = b >> 3;
        int lo = shard * shard_size;
        int hi = lo + shard_size;
        const int stride = (FILL_BLOCKS >> 3) * 256;
        int e = chunk * 256 + threadIdx.x;
        for (; e + 3 * stride < E; e += 4 * stride) {
            int d0 = dst[e];
            int d1 = dst[e + stride];
            int d2 = dst[e + 2 * stride];
            int d3 = dst[e + 3 * stride];
            int s0 = src[e];
            int s1 = src[e + stride];
            int s2 = src[e + 2 * stride];
            int s3 = src[e + 3 * stride];
            if (d0 >= lo && d0 < hi) {
                int p = atomicAdd(&cnt[d0], 1);
                if (p < CAP) slot[(size_t)d0 * CAP + p] = (ushort)s0;
            }
            if (d1 >= lo && d1 < hi) {
                int p = atomicAdd(&cnt[d1], 1);
                if (p < CAP) slot[(size_t)d1 * CAP + p] = (ushort)s1;
            }
            if (d2 >= lo && d2 < hi) {
                int p = atomicAdd(&cnt[d2], 1);
                if (p < CAP) slot[(size_t)d2 * CAP + p] = (ushort)s2;
            }
            if (d3 >= lo && d3 < hi) {
                int p = atomicAdd(&cnt[d3], 1);
                if (p < CAP) slot[(size_t)d3 * CAP + p] = (ushort)s3;
            }
        }
        for (; e < E; e += stride) {
            int d = dst[e];
            int s = src[e];
            if (d >= lo && d < hi) {
                int p = atomicAdd(&cnt[d], 1);
                if (p < CAP) slot[(size_t)d * CAP + p] = (ushort)s;
            }
        }
    } else if (b < FILL_BLOCKS + cast_blocks) {
        // ---- x (f32) -> Xb (bf16), 8 floats / thread ----
        int i = (b - FILL_BLOCKS) * 256 + threadIdx.x;
        if (i < n8) {
            const float4* xp = (const float4*)x;
            float4 v0 = xp[(size_t)i * 2];
            float4 v1 = xp[(size_t)i * 2 + 1];
            uint4 o;
            o.x = pack2bf(v0.x, v0.y);
            o.y = pack2bf(v0.z, v0.w);
            o.z = pack2bf(v1.x, v1.y);
            o.w = pack2bf(v1.z, v1.w);
            *(uint4*)&Xb[(size_t)i * 8] = o;
        }
    } else {
        // ---- pack stacked W = [Wself; Wneigh] (256x128) into MFMA B-frag layout ----
        // Wp[((ks*8+nt)*64+lane)*8+j] = W[ks*32+(lane>>4)*8+j][nt*16+(lane&15)]
        int gid = (b - FILL_BLOCKS - cast_blocks) * 256 + threadIdx.x;  // 0..65535
        int layer = gid >> 15;
        int r = gid & 32767;
        int j = r & 7;
        int lane = (r >> 3) & 63;
        int nt = (r >> 9) & 7;
        int ks = r >> 12;
        int k = ks * 32 + (lane >> 4) * 8 + j;
        int col = nt * 16 + (lane & 15);
        const float* W = layer ? (k < 128 ? W2a : W2b) : (k < 128 ? W1a : W1b);
        __hip_bfloat16 bf = __float2bfloat16(W[(k & 127) * DD + col]);
        (layer ? Wp2 : Wp1)[r] = *(ushort*)&bf;
    }
}

// ---------------- fused SAGE layer: agg(mean neigh)->LDS -> MFMA GEMM --------------
// One block = one 16-row strip. Each 16-lane GROUP owns one node end-to-end
// (16 lanes x 16 B = full 256 B row; accumulator lives across the degree walk).
// Agg loop = round-5 measured-best form (49.7us; round-6's 8-wide batches regressed
// to 51.3 via VGPR 40->56 / occupancy 48->34%). Converged ~50us across 3 structures:
// service-rate-bound on the compulsory 8-XCD x 12.8MB = ~112MB gather traffic.
__global__ __launch_bounds__(256) void sage_layer_kernel(
        const ushort* __restrict__ Xin, const int* __restrict__ cnt,
        const ushort* __restrict__ slot, const ushort* __restrict__ Wp,
        const float* __restrict__ bias,
        ushort* __restrict__ out_bf16, float* __restrict__ out_f32,
        int n, int do_elu) {
    __shared__ ushort hn[16 * LDSP];   // 4.25 KB

    const int row0 = blockIdx.x * 16;
    const int w    = threadIdx.x >> 6;   // wave 0..3
    const int lane = threadIdx.x & 63;
    const int g  = lane >> 4;            // group 0..3: owns node row0 + w*4 + g
    const int sl = lane & 15;
    const int c  = sl * 8;

    const int vg = row0 + w * 4 + g;
    int d = (vg < n) ? cnt[vg] : 0;
    if (d > CAP) d = CAP;

    // neighbor indices for this group's node: reg r holds slots r*16 + sl
    const ushort* sp = slot + (size_t)(vg < n ? vg : 0) * CAP;
    int idxv[4];
#pragma unroll
    for (int r = 0; r < 4; ++r) idxv[r] = sp[r * 16 + sl];

    float acc[8];
#pragma unroll
    for (int j = 0; j < 8; ++j) acc[j] = 0.f;

#pragma unroll
    for (int r = 0; r < 4; ++r) {            // chunks of 16 neighbors (static unroll)
        const int base = r * 16;
        if (base < d) {                      // group-uniform (exec-masked per group)
            const int nin = (d - base < 16) ? (d - base) : 16;   // 1..16
            for (int s = 0; s < nin; s += 4) {
                int c1 = s + 1 < nin, c2 = s + 2 < nin, c3 = s + 3 < nin;
                int u0 = __shfl(idxv[r], g * 16 + s);
                int u1 = __shfl(idxv[r], g * 16 + (c1 ? s + 1 : nin - 1));
                int u2 = __shfl(idxv[r], g * 16 + (c2 ? s + 2 : nin - 1));
                int u3 = __shfl(idxv[r], g * 16 + (c3 ? s + 3 : nin - 1));
                float w1 = c1 ? 1.f : 0.f;
                float w2 = c2 ? 1.f : 0.f;
                float w3 = c3 ? 1.f : 0.f;
                ushortx8 y0 = *(const ushortx8*)&Xin[(size_t)u0 * DD + c];
                ushortx8 y1 = *(const ushortx8*)&Xin[(size_t)u1 * DD + c];
                ushortx8 y2 = *(const ushortx8*)&Xin[(size_t)u2 * DD + c];
                ushortx8 y3 = *(const ushortx8*)&Xin[(size_t)u3 * DD + c];
#pragma unroll
                for (int j = 0; j < 8; ++j)
                    acc[j] += BF2F((ushort)y0[j]) + w1 * BF2F((ushort)y1[j])
                            + w2 * BF2F((ushort)y2[j]) + w3 * BF2F((ushort)y3[j]);
            }
        }
    }

    // write this group's aggregated row (no cross-group reduce needed)
    {
        float inv = 1.0f / (float)(d > 0 ? d : 1);
        ushort tmp[8];
#pragma unroll
        for (int j = 0; j < 8; ++j) {
            __hip_bfloat16 bq = __float2bfloat16(acc[j] * inv);
            tmp[j] = *(ushort*)&bq;
        }
        uint4 ov;
        ov.x = (unsigned)tmp[0] | ((unsigned)tmp[1] << 16);
        ov.y = (unsigned)tmp[2] | ((unsigned)tmp[3] << 16);
        ov.z = (unsigned)tmp[4] | ((unsigned)tmp[5] << 16);
        ov.w = (unsigned)tmp[6] | ((unsigned)tmp[7] << 16);
        *(uint4*)&hn[(w * 4 + g) * LDSP + c] = ov;   // 272 B row stride
    }

    __syncthreads();

    // ---- gemm: wave w owns N-tiles {2w, 2w+1}; K=256 = [Xin strip rows | hn] ----
    const int m = lane & 15;
    const int quad = lane >> 4;
    int mrow = row0 + m; if (mrow >= n) mrow = n - 1;
    const ushort* xrow = Xin + (size_t)mrow * DD + quad * 8;
    const ushort* hrow = &hn[m * LDSP + quad * 8];

    floatx4 acc0 = (floatx4){0.f, 0.f, 0.f, 0.f};
    floatx4 acc1 = (floatx4){0.f, 0.f, 0.f, 0.f};
#pragma unroll
    for (int ks = 0; ks < 8; ++ks) {
        short8 a = (ks < 4) ? *(const short8*)(xrow + ks * 32)
                            : *(const short8*)(hrow + (ks - 4) * 32);
        const ushort* wp = Wp + ((size_t)(ks * 8) * 64 + lane) * 8;
        short8 b0 = *(const short8*)(wp + (size_t)(w * 2 + 0) * 512);
        short8 b1 = *(const short8*)(wp + (size_t)(w * 2 + 1) * 512);
        acc0 = __builtin_amdgcn_mfma_f32_16x16x32_bf16(a, b0, acc0, 0, 0, 0);
        acc1 = __builtin_amdgcn_mfma_f32_16x16x32_bf16(a, b1, acc1, 0, 0, 0);
    }
    // C layout: col = nt*16 + (lane&15), row = quad*4 + reg
#pragma unroll
    for (int q = 0; q < 2; ++q) {
        int nt = w * 2 + q;
        int col = nt * 16 + m;
        float bv = bias[col];
        floatx4 av = q ? acc1 : acc0;
#pragma unroll
        for (int r = 0; r < 4; ++r) {
            int row = row0 + quad * 4 + r;
            if (row < n) {
                float vv = av[r] + bv;
                if (do_elu) vv = vv > 0.f ? vv : expm1f(vv);
                if (out_f32) {
                    out_f32[(size_t)row * DD + col] = vv;
                } else {
                    __hip_bfloat16 bq = __float2bfloat16(vv);
                    out_bf16[(size_t)row * DD + col] = *(ushort*)&bq;
                }
            }
        }
    }
}

// ---------------- launch ----------------

extern "C" void kernel_launch(void* const* d_in, const int* in_sizes, int n_in,
                              void* d_out, int out_size, void* d_ws, size_t ws_size,
                              hipStream_t stream) {
    const float* x   = (const float*)d_in[0];
    const int*   src = (const int*)d_in[1];
    const int*   dst = (const int*)d_in[2];
    const float* W1s = (const float*)d_in[3];
    const float* W1n = (const float*)d_in[4];
    const float* b1  = (const float*)d_in[5];
    const float* W2s = (const float*)d_in[6];
    const float* W2n = (const float*)d_in[7];
    const float* b2  = (const float*)d_in[8];
    float* out = (float*)d_out;

    const int N = in_sizes[0] / DD;
    const int E = in_sizes[1];

    char* ws = (char*)d_ws;
    int* cnt       = (int*)ws; ws += (size_t)N * 4;
    ushort* slot   = (ushort*)ws; ws += (size_t)N * CAP * 2;  // 6.4 MB (ushort src ids)
    ushort* Wp1    = (ushort*)ws; ws += 65536;                // 32768 bf16
    ushort* Wp2    = (ushort*)ws; ws += 65536;
    ushort* Xb     = (ushort*)ws; ws += (size_t)N * DD * 2;   // bf16 input
    ushort* H1     = (ushort*)ws; ws += (size_t)N * DD * 2;   // bf16 layer-1 output

    (void)hipMemsetAsync(cnt, 0, (size_t)N * 4, stream);

    // fused prep: sharded bucket fill + bf16 cast + W pack in ONE launch
    const int shard_size = (N + NSHARD - 1) / NSHARD;
    const int n8 = N * DD / 8;
    const int cast_blocks = (n8 + 255) / 256;
    prep_kernel<<<FILL_BLOCKS + cast_blocks + PACK_BLOCKS, 256, 0, stream>>>(
        x, src, dst, cnt, slot, W1s, W1n, W2s, W2n, Wp1, Wp2, Xb,
        E, n8, shard_size, cast_blocks);

    const int nstrips = (N + 15) / 16;              // 3125 (N=50000)

    // layer 1: H1 = ELU([Xb | mean_neigh(Xb)] @ W1 + b1)   (agg fused into gemm)
    sage_layer_kernel<<<nstrips, 256, 0, stream>>>(Xb, cnt, slot, Wp1, b1, H1, nullptr, N, 1);
    // layer 2: out = [H1 | mean_neigh(H1)] @ W2 + b2
    sage_layer_kernel<<<nstrips, 256, 0, stream>>>(H1, cnt, slot, Wp2, b2, nullptr, out, N, 0);
}

// Round 10
// 219.721 us; speedup vs baseline: 1.0150x; 1.0122x over previous
//
#include <hip/hip_runtime.h>
#include <hip/hip_bf16.h>
#include <math.h>

#define DD 128
#define CAP 64      // bucket capacity per node; deg ~ Poisson(16)
#define LDSP 136    // padded LDS row: 128+8 bf16 -> 272 B stride
#define NSHARD 8    // = #XCDs; shard = blockIdx&7 keeps cnt/slot region XCD-local
#define FILL_BLOCKS 4096   // 512 chunks x 8 shards (round-1 measured config)
#define PACK_BLOCKS 256

typedef __attribute__((ext_vector_type(8))) short short8;
typedef __attribute__((ext_vector_type(4))) float floatx4;
typedef __attribute__((ext_vector_type(8))) unsigned short ushortx8;

static __device__ __forceinline__ unsigned pack2bf(float a, float b) {
    __hip_bfloat16 ba = __float2bfloat16(a), bb = __float2bfloat16(b);
    return (unsigned)*(ushort*)&ba | ((unsigned)*(ushort*)&bb << 16);
}
#define BF2F(u) __uint_as_float((unsigned)(u) << 16)

// ---------------- fused prep: XCD-sharded CSR fill + x->bf16 cast + W pack ----------
// Fill: shard = b&7 (dst range stays in one XCD's L2 so scatter stores coalesce
// there — round 2 measured un-sharded at +16MB WRITE / +14us). slot is ushort.
// src loads hoisted next to dst loads (8 independent loads before branch/atomic).
// NOTE: __builtin_nontemporal_* killed the container in rounds 7 AND 8 — banned.
__global__ __launch_bounds__(256) void prep_kernel(
        const float* __restrict__ x,
        const int* __restrict__ src, const int* __restrict__ dst,
        int* __restrict__ cnt, ushort* __restrict__ slot,
        const float* __restrict__ W1a, const float* __restrict__ W1b,
        const float* __restrict__ W2a, const float* __restrict__ W2b,
        ushort* __restrict__ Wp1, ushort* __restrict__ Wp2,
        ushort* __restrict__ Xb,
        int E, int n8, int shard_size, int cast_blocks) {
    int b = blockIdx.x;
    if (b < FILL_BLOCKS) {
        int shard = b & (NSHARD - 1);
        int chunk = b >> 3;
        int lo = shard * shard_size;
        int hi = lo + shard_size;
        const int stride = (FILL_BLOCKS >> 3) * 256;
        int e = chunk * 256 + threadIdx.x;
        for (; e + 3 * stride < E; e += 4 * stride) {
            int d0 = dst[e];
            int d1 = dst[e + stride];
            int d2 = dst[e + 2 * stride];
            int d3 = dst[e + 3 * stride];
            int s0 = src[e];
            int s1 = src[e + stride];
            int s2 = src[e + 2 * stride];
            int s3 = src[e + 3 * stride];
            if (d0 >= lo && d0 < hi) {
                int p = atomicAdd(&cnt[d0], 1);
                if (p < CAP) slot[(size_t)d0 * CAP + p] = (ushort)s0;
            }
            if (d1 >= lo && d1 < hi) {
                int p = atomicAdd(&cnt[d1], 1);
                if (p < CAP) slot[(size_t)d1 * CAP + p] = (ushort)s1;
            }
            if (d2 >= lo && d2 < hi) {
                int p = atomicAdd(&cnt[d2], 1);
                if (p < CAP) slot[(size_t)d2 * CAP + p] = (ushort)s2;
            }
            if (d3 >= lo && d3 < hi) {
                int p = atomicAdd(&cnt[d3], 1);
                if (p < CAP) slot[(size_t)d3 * CAP + p] = (ushort)s3;
            }
        }
        for (; e < E; e += stride) {
            int d = dst[e];
            int s = src[e];
            if (d >= lo && d < hi) {
                int p = atomicAdd(&cnt[d], 1);
                if (p < CAP) slot[(size_t)d * CAP + p] = (ushort)s;
            }
        }
    } else if (b < FILL_BLOCKS + cast_blocks) {
        // ---- x (f32) -> Xb (bf16), 8 floats / thread ----
        int i = (b - FILL_BLOCKS) * 256 + threadIdx.x;
        if (i < n8) {
            const float4* xp = (const float4*)x;
            float4 v0 = xp[(size_t)i * 2];
            float4 v1 = xp[(size_t)i * 2 + 1];
            uint4 o;
            o.x = pack2bf(v0.x, v0.y);
            o.y = pack2bf(v0.z, v0.w);
            o.z = pack2bf(v1.x, v1.y);
            o.w = pack2bf(v1.z, v1.w);
            *(uint4*)&Xb[(size_t)i * 8] = o;
        }
    } else {
        // ---- pack stacked W = [Wself; Wneigh] (256x128) into MFMA B-frag layout ----
        // Wp[((ks*8+nt)*64+lane)*8+j] = W[ks*32+(lane>>4)*8+j][nt*16+(lane&15)]
        int gid = (b - FILL_BLOCKS - cast_blocks) * 256 + threadIdx.x;  // 0..65535
        int layer = gid >> 15;
        int r = gid & 32767;
        int j = r & 7;
        int lane = (r >> 3) & 63;
        int nt = (r >> 9) & 7;
        int ks = r >> 12;
        int k = ks * 32 + (lane >> 4) * 8 + j;
        int col = nt * 16 + (lane & 15);
        const float* W = layer ? (k < 128 ? W2a : W2b) : (k < 128 ? W1a : W1b);
        __hip_bfloat16 bf = __float2bfloat16(W[(k & 127) * DD + col]);
        (layer ? Wp2 : Wp1)[r] = *(ushort*)&bf;
    }
}

// ---------------- fused SAGE layer: agg(mean neigh)->LDS -> MFMA GEMM --------------
// One block = one 16-row strip. Each 16-lane GROUP owns one node end-to-end
// (16 lanes x 16 B = full 256 B row; accumulator lives across the degree walk).
// Agg loop = round-5 measured-best form. Converged ~50-52us across 3 structures.
// NEW (round 10): __launch_bounds__(256, 8) — request 8 blocks/CU (was running at
// OccupancyPercent ~50% = 16 waves/CU with nothing structurally blocking 32:
// VGPR 40 <= 64, LDS 4.6KB x 8 = 37KB << 160KB). If the gather has a latency
// component, 2x resident waves => 2x outstanding bytes/CU => higher service rate.
__global__ __launch_bounds__(256, 8) void sage_layer_kernel(
        const ushort* __restrict__ Xin, const int* __restrict__ cnt,
        const ushort* __restrict__ slot, const ushort* __restrict__ Wp,
        const float* __restrict__ bias,
        ushort* __restrict__ out_bf16, float* __restrict__ out_f32,
        int n, int do_elu) {
    __shared__ ushort hn[16 * LDSP];   // 4.25 KB

    const int row0 = blockIdx.x * 16;
    const int w    = threadIdx.x >> 6;   // wave 0..3
    const int lane = threadIdx.x & 63;
    const int g  = lane >> 4;            // group 0..3: owns node row0 + w*4 + g
    const int sl = lane & 15;
    const int c  = sl * 8;

    const int vg = row0 + w * 4 + g;
    int d = (vg < n) ? cnt[vg] : 0;
    if (d > CAP) d = CAP;

    // neighbor indices for this group's node: reg r holds slots r*16 + sl
    const ushort* sp = slot + (size_t)(vg < n ? vg : 0) * CAP;
    int idxv[4];
#pragma unroll
    for (int r = 0; r < 4; ++r) idxv[r] = sp[r * 16 + sl];

    float acc[8];
#pragma unroll
    for (int j = 0; j < 8; ++j) acc[j] = 0.f;

#pragma unroll
    for (int r = 0; r < 4; ++r) {            // chunks of 16 neighbors (static unroll)
        const int base = r * 16;
        if (base < d) {                      // group-uniform (exec-masked per group)
            const int nin = (d - base < 16) ? (d - base) : 16;   // 1..16
            for (int s = 0; s < nin; s += 4) {
                int c1 = s + 1 < nin, c2 = s + 2 < nin, c3 = s + 3 < nin;
                int u0 = __shfl(idxv[r], g * 16 + s);
                int u1 = __shfl(idxv[r], g * 16 + (c1 ? s + 1 : nin - 1));
                int u2 = __shfl(idxv[r], g * 16 + (c2 ? s + 2 : nin - 1));
                int u3 = __shfl(idxv[r], g * 16 + (c3 ? s + 3 : nin - 1));
                float w1 = c1 ? 1.f : 0.f;
                float w2 = c2 ? 1.f : 0.f;
                float w3 = c3 ? 1.f : 0.f;
                ushortx8 y0 = *(const ushortx8*)&Xin[(size_t)u0 * DD + c];
                ushortx8 y1 = *(const ushortx8*)&Xin[(size_t)u1 * DD + c];
                ushortx8 y2 = *(const ushortx8*)&Xin[(size_t)u2 * DD + c];
                ushortx8 y3 = *(const ushortx8*)&Xin[(size_t)u3 * DD + c];
#pragma unroll
                for (int j = 0; j < 8; ++j)
                    acc[j] += BF2F((ushort)y0[j]) + w1 * BF2F((ushort)y1[j])
                            + w2 * BF2F((ushort)y2[j]) + w3 * BF2F((ushort)y3[j]);
            }
        }
    }

    // write this group's aggregated row (no cross-group reduce needed)
    {
        float inv = 1.0f / (float)(d > 0 ? d : 1);
        ushort tmp[8];
#pragma unroll
        for (int j = 0; j < 8; ++j) {
            __hip_bfloat16 bq = __float2bfloat16(acc[j] * inv);
            tmp[j] = *(ushort*)&bq;
        }
        uint4 ov;
        ov.x = (unsigned)tmp[0] | ((unsigned)tmp[1] << 16);
        ov.y = (unsigned)tmp[2] | ((unsigned)tmp[3] << 16);
        ov.z = (unsigned)tmp[4] | ((unsigned)tmp[5] << 16);
        ov.w = (unsigned)tmp[6] | ((unsigned)tmp[7] << 16);
        *(uint4*)&hn[(w * 4 + g) * LDSP + c] = ov;   // 272 B row stride
    }

    __syncthreads();

    // ---- gemm: wave w owns N-tiles {2w, 2w+1}; K=256 = [Xin strip rows | hn] ----
    const int m = lane & 15;
    const int quad = lane >> 4;
    int mrow = row0 + m; if (mrow >= n) mrow = n - 1;
    const ushort* xrow = Xin + (size_t)mrow * DD + quad * 8;
    const ushort* hrow = &hn[m * LDSP + quad * 8];

    floatx4 acc0 = (floatx4){0.f, 0.f, 0.f, 0.f};
    floatx4 acc1 = (floatx4){0.f, 0.f, 0.f, 0.f};
#pragma unroll
    for (int ks = 0; ks < 8; ++ks) {
        short8 a = (ks < 4) ? *(const short8*)(xrow + ks * 32)
                            : *(const short8*)(hrow + (ks - 4) * 32);
        const ushort* wp = Wp + ((size_t)(ks * 8) * 64 + lane) * 8;
        short8 b0 = *(const short8*)(wp + (size_t)(w * 2 + 0) * 512);
        short8 b1 = *(const short8*)(wp + (size_t)(w * 2 + 1) * 512);
        acc0 = __builtin_amdgcn_mfma_f32_16x16x32_bf16(a, b0, acc0, 0, 0, 0);
        acc1 = __builtin_amdgcn_mfma_f32_16x16x32_bf16(a, b1, acc1, 0, 0, 0);
    }
    // C layout: col = nt*16 + (lane&15), row = quad*4 + reg
#pragma unroll
    for (int q = 0; q < 2; ++q) {
        int nt = w * 2 + q;
        int col = nt * 16 + m;
        float bv = bias[col];
        floatx4 av = q ? acc1 : acc0;
#pragma unroll
        for (int r = 0; r < 4; ++r) {
            int row = row0 + quad * 4 + r;
            if (row < n) {
                float vv = av[r] + bv;
                if (do_elu) vv = vv > 0.f ? vv : expm1f(vv);
                if (out_f32) {
                    out_f32[(size_t)row * DD + col] = vv;
                } else {
                    __hip_bfloat16 bq = __float2bfloat16(vv);
                    out_bf16[(size_t)row * DD + col] = *(ushort*)&bq;
                }
            }
        }
    }
}

// ---------------- launch ----------------

extern "C" void kernel_launch(void* const* d_in, const int* in_sizes, int n_in,
                              void* d_out, int out_size, void* d_ws, size_t ws_size,
                              hipStream_t stream) {
    const float* x   = (const float*)d_in[0];
    const int*   src = (const int*)d_in[1];
    const int*   dst = (const int*)d_in[2];
    const float* W1s = (const float*)d_in[3];
    const float* W1n = (const float*)d_in[4];
    const float* b1  = (const float*)d_in[5];
    const float* W2s = (const float*)d_in[6];
    const float* W2n = (const float*)d_in[7];
    const float* b2  = (const float*)d_in[8];
    float* out = (float*)d_out;

    const int N = in_sizes[0] / DD;
    const int E = in_sizes[1];

    char* ws = (char*)d_ws;
    int* cnt       = (int*)ws; ws += (size_t)N * 4;
    ushort* slot   = (ushort*)ws; ws += (size_t)N * CAP * 2;  // 6.4 MB (ushort src ids)
    ushort* Wp1    = (ushort*)ws; ws += 65536;                // 32768 bf16
    ushort* Wp2    = (ushort*)ws; ws += 65536;
    ushort* Xb     = (ushort*)ws; ws += (size_t)N * DD * 2;   // bf16 input
    ushort* H1     = (ushort*)ws; ws += (size_t)N * DD * 2;   // bf16 layer-1 output

    (void)hipMemsetAsync(cnt, 0, (size_t)N * 4, stream);

    // fused prep: sharded bucket fill + bf16 cast + W pack in ONE launch
    const int shard_size = (N + NSHARD - 1) / NSHARD;
    const int n8 = N * DD / 8;
    const int cast_blocks = (n8 + 255) / 256;
    prep_kernel<<<FILL_BLOCKS + cast_blocks + PACK_BLOCKS, 256, 0, stream>>>(
        x, src, dst, cnt, slot, W1s, W1n, W2s, W2n, Wp1, Wp2, Xb,
        E, n8, shard_size, cast_blocks);

    const int nstrips = (N + 15) / 16;              // 3125 (N=50000)

    // layer 1: H1 = ELU([Xb | mean_neigh(Xb)] @ W1 + b1)   (agg fused into gemm)
    sage_layer_kernel<<<nstrips, 256, 0, stream>>>(Xb, cnt, slot, Wp1, b1, H1, nullptr, N, 1);
    // layer 2: out = [H1 | mean_neigh(H1)] @ W2 + b2
    sage_layer_kernel<<<nstrips, 256, 0, stream>>>(H1, cnt, slot, Wp2, b2, nullptr, out, N, 0);
}